// Round 1
// baseline (976.771 us; speedup 1.0000x reference)
//
#include <hip/hip_runtime.h>

namespace {
constexpr int Bn = 8;
constexpr int Sn = 1024;
constexpr int Dn = 1024;
constexpr int Hn = 16;
constexpr int DPH = 64;   // Dn / Hn
constexpr int QB  = 64;   // q rows per block (16 per wave)
constexpr int KB  = 64;   // k cols per tile
constexpr float QSCALE    = 0.125f;      // 1/sqrt(dph)
constexpr float DROPSCALE = 1.0f / 0.9f; // 1/(1-p_drop)

typedef __attribute__((ext_vector_type(4))) float    f32x4;
typedef __attribute__((ext_vector_type(8))) _Float16 f16x8;
typedef __attribute__((ext_vector_type(4))) _Float16 f16x4;
}

__global__ __launch_bounds__(256)
void mha_fwd(const float* __restrict__ Q, const float* __restrict__ K,
             const float* __restrict__ V, const int* __restrict__ msk,
             const float* __restrict__ dmask, float* __restrict__ out)
{
    // +8 halves pad: keeps rows 16B-aligned (stride 144B) and off the 128B bank stride
    __shared__ __align__(16) _Float16 Ql[QB][DPH + 8];
    __shared__ __align__(16) _Float16 Kl[KB][DPH + 8];
    __shared__ __align__(16) _Float16 Vt[DPH][KB + 8];   // V transposed: [d][k]
    __shared__ __align__(16) _Float16 Pl[4][16][KB + 8]; // per-wave P strip

    const int tid = threadIdx.x;
    const int w   = tid >> 6;        // wave id, owns q rows [w*16, w*16+16)
    const int l   = tid & 63;
    const int fr  = l & 15;          // A-row / B-col within a 16x16 tile
    const int kg  = (l >> 4) << 3;   // K-dim element base for A/B frags
    const int rg  = (l >> 4) << 2;   // C-frag row base

    const int bid = blockIdx.x;
    const int qt = bid & (Sn / QB - 1);
    const int h  = (bid >> 4) & (Hn - 1);
    const int b  = bid >> 8;
    const int qbase = qt * QB;

    // ---- stage Q (pre-scaled) to LDS f16 ----
    {
        const int row = tid >> 2;          // 0..63
        const int seg = (tid & 3) << 4;    // 0,16,32,48
        const float4* gq = reinterpret_cast<const float4*>(
            Q + ((size_t)(b * Sn + qbase + row)) * Dn + h * DPH + seg);
        #pragma unroll
        for (int i = 0; i < 4; ++i) {
            float4 v = gq[i];
            f16x4 qp;
            qp[0] = (_Float16)(v.x * QSCALE);
            qp[1] = (_Float16)(v.y * QSCALE);
            qp[2] = (_Float16)(v.z * QSCALE);
            qp[3] = (_Float16)(v.w * QSCALE);
            *reinterpret_cast<f16x4*>(&Ql[row][seg + i * 4]) = qp;
        }
    }
    __syncthreads();

    // Q fragments live in registers for the whole k-loop
    f16x8 qf0 = *reinterpret_cast<const f16x8*>(&Ql[w * 16 + fr][kg]);
    f16x8 qf1 = *reinterpret_cast<const f16x8*>(&Ql[w * 16 + fr][32 + kg]);

    f32x4 acc[4];
    #pragma unroll
    for (int dt = 0; dt < 4; ++dt) acc[dt] = (f32x4){0.f, 0.f, 0.f, 0.f};
    float m_r[4] = {-INFINITY, -INFINITY, -INFINITY, -INFINITY};
    float l_r[4] = {0.f, 0.f, 0.f, 0.f};

    const float* dm_base = dmask + ((size_t)(b * Hn + h)) * Sn * Sn
                         + (size_t)(qbase + w * 16) * Sn;

    #pragma unroll 1
    for (int kt = 0; kt < Sn / KB; ++kt) {
        __syncthreads();   // previous iteration's Kl/Vt reads done
        // ---- stage K tile (row-major) and V tile (transposed) ----
        {
            const int row = tid >> 2;
            const int seg = (tid & 3) << 4;
            const size_t goff = ((size_t)(b * Sn + kt * KB + row)) * Dn + h * DPH + seg;
            const float4* gk = reinterpret_cast<const float4*>(K + goff);
            const float4* gv = reinterpret_cast<const float4*>(V + goff);
            #pragma unroll
            for (int i = 0; i < 4; ++i) {
                float4 kv = gk[i];
                f16x4 kp;
                kp[0] = (_Float16)kv.x; kp[1] = (_Float16)kv.y;
                kp[2] = (_Float16)kv.z; kp[3] = (_Float16)kv.w;
                *reinterpret_cast<f16x4*>(&Kl[row][seg + i * 4]) = kp;
                float4 vv = gv[i];
                Vt[seg + i * 4 + 0][row] = (_Float16)vv.x;
                Vt[seg + i * 4 + 1][row] = (_Float16)vv.y;
                Vt[seg + i * 4 + 2][row] = (_Float16)vv.z;
                Vt[seg + i * 4 + 3][row] = (_Float16)vv.w;
            }
        }
        __syncthreads();

        // ---- QK^T: 16 q rows x 64 k cols per wave ----
        f32x4 sc[4];
        #pragma unroll
        for (int ct = 0; ct < 4; ++ct) {
            f16x8 kf0 = *reinterpret_cast<const f16x8*>(&Kl[ct * 16 + fr][kg]);
            f16x8 kf1 = *reinterpret_cast<const f16x8*>(&Kl[ct * 16 + fr][32 + kg]);
            f32x4 z = {0.f, 0.f, 0.f, 0.f};
            z = __builtin_amdgcn_mfma_f32_16x16x32_f16(qf0, kf0, z, 0, 0, 0);
            z = __builtin_amdgcn_mfma_f32_16x16x32_f16(qf1, kf1, z, 0, 0, 0);
            sc[ct] = z;
        }
        // ---- key mask: mask==0 -> -1e20 (per column) ----
        #pragma unroll
        for (int ct = 0; ct < 4; ++ct) {
            if (msk[b * Sn + kt * KB + ct * 16 + fr] == 0) {
                #pragma unroll
                for (int r = 0; r < 4; ++r) sc[ct][r] = -1e20f;
            }
        }
        // ---- online softmax (per q-row; rows live in 16-lane groups) ----
        float tm[4];
        #pragma unroll
        for (int r = 0; r < 4; ++r)
            tm[r] = fmaxf(fmaxf(sc[0][r], sc[1][r]), fmaxf(sc[2][r], sc[3][r]));
        #pragma unroll
        for (int off = 1; off < 16; off <<= 1) {
            #pragma unroll
            for (int r = 0; r < 4; ++r)
                tm[r] = fmaxf(tm[r], __shfl_xor(tm[r], off));
        }
        float al[4];
        #pragma unroll
        for (int r = 0; r < 4; ++r) {
            float mn = fmaxf(m_r[r], tm[r]);
            al[r] = __expf(m_r[r] - mn);   // exp(-inf)=0 first tile
            m_r[r] = mn;
        }
        float p[4][4];
        float rs[4] = {0.f, 0.f, 0.f, 0.f};
        #pragma unroll
        for (int ct = 0; ct < 4; ++ct) {
            #pragma unroll
            for (int r = 0; r < 4; ++r) {
                p[ct][r] = __expf(sc[ct][r] - m_r[r]);
                rs[r] += p[ct][r];          // denominator EXCLUDES dropout
            }
        }
        #pragma unroll
        for (int off = 1; off < 16; off <<= 1) {
            #pragma unroll
            for (int r = 0; r < 4; ++r)
                rs[r] += __shfl_xor(rs[r], off);
        }
        #pragma unroll
        for (int r = 0; r < 4; ++r)
            l_r[r] = l_r[r] * al[r] + rs[r];
        #pragma unroll
        for (int dt = 0; dt < 4; ++dt) {
            #pragma unroll
            for (int r = 0; r < 4; ++r) acc[dt][r] *= al[r];
        }
        // ---- dropout on numerator, P -> per-wave LDS strip (f16) ----
        #pragma unroll
        for (int r = 0; r < 4; ++r) {
            const float* dmrow = dm_base + (size_t)(rg + r) * Sn + kt * KB;
            #pragma unroll
            for (int ct = 0; ct < 4; ++ct) {
                float pd = p[ct][r] * dmrow[ct * 16 + fr];
                Pl[w][rg + r][ct * 16 + fr] = (_Float16)pd;
            }
        }
        // ---- PV: acc += P @ V  (wave-private Pl, no barrier needed) ----
        f16x8 pf0 = *reinterpret_cast<const f16x8*>(&Pl[w][fr][kg]);
        f16x8 pf1 = *reinterpret_cast<const f16x8*>(&Pl[w][fr][32 + kg]);
        #pragma unroll
        for (int dt = 0; dt < 4; ++dt) {
            f16x8 vf0 = *reinterpret_cast<const f16x8*>(&Vt[dt * 16 + fr][kg]);
            f16x8 vf1 = *reinterpret_cast<const f16x8*>(&Vt[dt * 16 + fr][32 + kg]);
            acc[dt] = __builtin_amdgcn_mfma_f32_16x16x32_f16(pf0, vf0, acc[dt], 0, 0, 0);
            acc[dt] = __builtin_amdgcn_mfma_f32_16x16x32_f16(pf1, vf1, acc[dt], 0, 0, 0);
        }
    }

    // ---- epilogue: out = acc * (1/(1-p)) / l ----
    #pragma unroll
    for (int r = 0; r < 4; ++r) {
        float inv = DROPSCALE / l_r[r];
        float* orow = out + ((size_t)(b * Sn + qbase + w * 16 + rg + r)) * Dn + h * DPH;
        #pragma unroll
        for (int dt = 0; dt < 4; ++dt)
            orow[dt * 16 + fr] = acc[dt][r] * inv;
    }
}

extern "C" void kernel_launch(void* const* d_in, const int* in_sizes, int n_in,
                              void* d_out, int out_size, void* d_ws, size_t ws_size,
                              hipStream_t stream)
{
    (void)in_sizes; (void)n_in; (void)out_size; (void)d_ws; (void)ws_size;
    const float* Q   = (const float*)d_in[0];
    const float* K   = (const float*)d_in[1];
    const float* V   = (const float*)d_in[2];
    const int*   msk = (const int*)d_in[3];
    const float* dm  = (const float*)d_in[4];
    float* o = (float*)d_out;

    dim3 grid(Bn * Hn * (Sn / QB));   // 8*16*16 = 2048 blocks
    dim3 block(256);                  // 4 waves
    mha_fwd<<<grid, block, 0, stream>>>(Q, K, V, msk, dm, o);
}

// Round 2
// 813.775 us; speedup vs baseline: 1.2003x; 1.2003x over previous
//
#include <hip/hip_runtime.h>

namespace {
constexpr int Bn = 8;
constexpr int Sn = 1024;
constexpr int Dn = 1024;
constexpr int Hn = 16;
constexpr int DPH = 64;   // Dn / Hn
constexpr int QB  = 64;   // q rows per block (16 per wave)
constexpr int KB  = 64;   // k cols per tile
constexpr int NT  = Sn / KB;  // 16 k-tiles
// fold 1/sqrt(dph) AND log2(e) into Q so softmax runs in exp2 domain
constexpr float QSCALE    = 0.125f * 1.44269504088896340736f;
constexpr float DROPSCALE = 1.0f / 0.9f;

typedef __attribute__((ext_vector_type(4))) float    f32x4;
typedef __attribute__((ext_vector_type(8))) _Float16 f16x8;
typedef __attribute__((ext_vector_type(4))) _Float16 f16x4;
typedef __attribute__((ext_vector_type(2))) _Float16 f16x2;
}

__device__ __forceinline__ float exp2_fast(float x) {
    float r;
    asm("v_exp_f32 %0, %1" : "=v"(r) : "v"(x));
    return r;
}

__global__ __launch_bounds__(256, 4)
void mha_fwd(const float* __restrict__ Q, const float* __restrict__ K,
             const float* __restrict__ V, const int* __restrict__ msk,
             const float* __restrict__ dmask, float* __restrict__ out)
{
    // +8 halves pad: 16B-aligned rows (144B stride), breaks 128B bank stride on reads
    __shared__ __align__(16) _Float16 Kl[KB][DPH + 8];
    __shared__ __align__(16) _Float16 Vt[DPH][KB + 8];   // V transposed: [d][k]
    __shared__ __align__(16) _Float16 Pl[4][16][KB + 8]; // per-wave P strip

    const int tid = threadIdx.x;
    const int w   = tid >> 6;        // wave id, owns q rows [w*16, w*16+16)
    const int l   = tid & 63;
    const int fr  = l & 15;          // A-row / B-col within a 16x16 tile
    const int kg  = (l >> 4) << 3;   // K-dim element base for A/B frags
    const int rg  = (l >> 4) << 2;   // C-frag row base

    const int bid = blockIdx.x;
    const int qt = bid & (Sn / QB - 1);
    const int h  = (bid >> 4) & (Hn - 1);
    const int b  = bid >> 8;
    const int qbase = qt * QB;

    // ---- Q fragments: one-time direct global->reg load (pre-scaled) ----
    f16x8 qf0, qf1;
    {
        const float* qp = Q + ((size_t)(b * Sn + qbase + w * 16 + fr)) * Dn + h * DPH;
        float4 a0 = *reinterpret_cast<const float4*>(qp + kg);
        float4 a1 = *reinterpret_cast<const float4*>(qp + kg + 4);
        float4 b0 = *reinterpret_cast<const float4*>(qp + 32 + kg);
        float4 b1 = *reinterpret_cast<const float4*>(qp + 32 + kg + 4);
        qf0[0] = (_Float16)(a0.x * QSCALE); qf0[1] = (_Float16)(a0.y * QSCALE);
        qf0[2] = (_Float16)(a0.z * QSCALE); qf0[3] = (_Float16)(a0.w * QSCALE);
        qf0[4] = (_Float16)(a1.x * QSCALE); qf0[5] = (_Float16)(a1.y * QSCALE);
        qf0[6] = (_Float16)(a1.z * QSCALE); qf0[7] = (_Float16)(a1.w * QSCALE);
        qf1[0] = (_Float16)(b0.x * QSCALE); qf1[1] = (_Float16)(b0.y * QSCALE);
        qf1[2] = (_Float16)(b0.z * QSCALE); qf1[3] = (_Float16)(b0.w * QSCALE);
        qf1[4] = (_Float16)(b1.x * QSCALE); qf1[5] = (_Float16)(b1.y * QSCALE);
        qf1[6] = (_Float16)(b1.z * QSCALE); qf1[7] = (_Float16)(b1.w * QSCALE);
    }

    // ---- staging / prefetch state ----
    const int srow = tid >> 2;          // 0..63
    const int sseg = (tid & 3) << 4;    // 0,16,32,48
    float4 kreg[4], vreg[4];            // K/V tile in flight (reg-staged, T14)
    int    mcur[4], mnxt[4];            // key-mask double buffer
    f16x2  dmh[8];                      // dropout tile in flight (0/1 -> f16 exact)

    const float* dm_base = dmask + ((size_t)(b * Hn + h)) * Sn * Sn
                         + (size_t)(qbase + w * 16) * Sn;

    auto kv_load = [&](int kt) {
        const size_t goff = ((size_t)(b * Sn + kt * KB + srow)) * Dn + h * DPH + sseg;
        const float4* gk = reinterpret_cast<const float4*>(K + goff);
        const float4* gv = reinterpret_cast<const float4*>(V + goff);
        #pragma unroll
        for (int i = 0; i < 4; ++i) { kreg[i] = gk[i]; vreg[i] = gv[i]; }
    };
    auto kv_store = [&]() {
        #pragma unroll
        for (int i = 0; i < 4; ++i) {
            f16x4 kp;
            kp[0] = (_Float16)kreg[i].x; kp[1] = (_Float16)kreg[i].y;
            kp[2] = (_Float16)kreg[i].z; kp[3] = (_Float16)kreg[i].w;
            *reinterpret_cast<f16x4*>(&Kl[srow][sseg + i * 4]) = kp;
            Vt[sseg + i * 4 + 0][srow] = (_Float16)vreg[i].x;
            Vt[sseg + i * 4 + 1][srow] = (_Float16)vreg[i].y;
            Vt[sseg + i * 4 + 2][srow] = (_Float16)vreg[i].z;
            Vt[sseg + i * 4 + 3][srow] = (_Float16)vreg[i].w;
        }
    };
    auto dm_load = [&](int kt) {
        #pragma unroll
        for (int r = 0; r < 4; ++r) {
            const float* dmrow = dm_base + (size_t)(rg + r) * Sn + kt * KB;
            #pragma unroll
            for (int ct = 0; ct < 4; ++ct) {
                const int idx = r * 4 + ct;
                dmh[idx >> 1][idx & 1] = (_Float16)dmrow[ct * 16 + fr];
            }
        }
    };
    auto msk_load = [&](int kt, int* dst) {
        #pragma unroll
        for (int ct = 0; ct < 4; ++ct)
            dst[ct] = msk[b * Sn + kt * KB + ct * 16 + fr];
    };

    // ---- prologue: prime the pipeline for tile 0 ----
    kv_load(0);
    dm_load(0);
    msk_load(0, mcur);

    f32x4 acc[4];
    #pragma unroll
    for (int dt = 0; dt < 4; ++dt) acc[dt] = (f32x4){0.f, 0.f, 0.f, 0.f};
    float m_r[4] = {-INFINITY, -INFINITY, -INFINITY, -INFINITY};
    float l_r[4] = {0.f, 0.f, 0.f, 0.f};

    #pragma unroll 1
    for (int kt = 0; kt < NT; ++kt) {
        __syncthreads();   // previous tile's Kl/Vt reads done
        kv_store();        // regs (tile kt) -> LDS, f32->f16
        if (kt + 1 < NT) { // issue next tile's global loads NOW (consumed next iter)
            kv_load(kt + 1);
            msk_load(kt + 1, mnxt);
        }
        __syncthreads();

        // ---- QK^T: 16 q rows x 64 k cols per wave (scores in log2 domain) ----
        f32x4 sc[4];
        #pragma unroll
        for (int ct = 0; ct < 4; ++ct) {
            f16x8 kf0 = *reinterpret_cast<const f16x8*>(&Kl[ct * 16 + fr][kg]);
            f16x8 kf1 = *reinterpret_cast<const f16x8*>(&Kl[ct * 16 + fr][32 + kg]);
            f32x4 z = {0.f, 0.f, 0.f, 0.f};
            z = __builtin_amdgcn_mfma_f32_16x16x32_f16(qf0, kf0, z, 0, 0, 0);
            z = __builtin_amdgcn_mfma_f32_16x16x32_f16(qf1, kf1, z, 0, 0, 0);
            sc[ct] = z;
        }
        // ---- key mask (prefetched): mask==0 -> -1e20 ----
        #pragma unroll
        for (int ct = 0; ct < 4; ++ct) {
            if (mcur[ct] == 0) {
                #pragma unroll
                for (int r = 0; r < 4; ++r) sc[ct][r] = -1e20f;
            }
        }
        // ---- online softmax, exp2 domain ----
        float tm[4];
        #pragma unroll
        for (int r = 0; r < 4; ++r)
            tm[r] = fmaxf(fmaxf(sc[0][r], sc[1][r]), fmaxf(sc[2][r], sc[3][r]));
        #pragma unroll
        for (int off = 1; off < 16; off <<= 1) {
            #pragma unroll
            for (int r = 0; r < 4; ++r)
                tm[r] = fmaxf(tm[r], __shfl_xor(tm[r], off));
        }
        float al[4];
        #pragma unroll
        for (int r = 0; r < 4; ++r) {
            float mn = fmaxf(m_r[r], tm[r]);
            al[r] = exp2_fast(m_r[r] - mn);   // exp2(-inf)=0 first tile
            m_r[r] = mn;
        }
        float p[4][4];
        float rs[4] = {0.f, 0.f, 0.f, 0.f};
        #pragma unroll
        for (int ct = 0; ct < 4; ++ct) {
            #pragma unroll
            for (int r = 0; r < 4; ++r) {
                p[ct][r] = exp2_fast(sc[ct][r] - m_r[r]);
                rs[r] += p[ct][r];            // denominator EXCLUDES dropout
            }
        }
        #pragma unroll
        for (int off = 1; off < 16; off <<= 1) {
            #pragma unroll
            for (int r = 0; r < 4; ++r)
                rs[r] += __shfl_xor(rs[r], off);
        }
        #pragma unroll
        for (int r = 0; r < 4; ++r)
            l_r[r] = l_r[r] * al[r] + rs[r];
        #pragma unroll
        for (int dt = 0; dt < 4; ++dt) {
            #pragma unroll
            for (int r = 0; r < 4; ++r) acc[dt][r] *= al[r];
        }
        // ---- dropout on numerator (prefetched f16 0/1 mask), P -> LDS strip ----
        #pragma unroll
        for (int r = 0; r < 4; ++r) {
            #pragma unroll
            for (int ct = 0; ct < 4; ++ct) {
                const int idx = r * 4 + ct;
                _Float16 ph = (_Float16)p[ct][r] * dmh[idx >> 1][idx & 1];
                Pl[w][rg + r][ct * 16 + fr] = ph;
            }
        }
        if (kt + 1 < NT) dm_load(kt + 1);  // issue dropout prefetch; overlaps PV+next stage
        // ---- PV: acc += P @ V  (wave-private Pl, no barrier needed) ----
        f16x8 pf0 = *reinterpret_cast<const f16x8*>(&Pl[w][fr][kg]);
        f16x8 pf1 = *reinterpret_cast<const f16x8*>(&Pl[w][fr][32 + kg]);
        #pragma unroll
        for (int dt = 0; dt < 4; ++dt) {
            f16x8 vf0 = *reinterpret_cast<const f16x8*>(&Vt[dt * 16 + fr][kg]);
            f16x8 vf1 = *reinterpret_cast<const f16x8*>(&Vt[dt * 16 + fr][32 + kg]);
            acc[dt] = __builtin_amdgcn_mfma_f32_16x16x32_f16(pf0, vf0, acc[dt], 0, 0, 0);
            acc[dt] = __builtin_amdgcn_mfma_f32_16x16x32_f16(pf1, vf1, acc[dt], 0, 0, 0);
        }
        // rotate mask buffer
        #pragma unroll
        for (int ct = 0; ct < 4; ++ct) mcur[ct] = mnxt[ct];
    }

    // ---- epilogue: out = acc * (1/(1-p)) / l ----
    #pragma unroll
    for (int r = 0; r < 4; ++r) {
        float inv = DROPSCALE / l_r[r];
        float* orow = out + ((size_t)(b * Sn + qbase + w * 16 + rg + r)) * Dn + h * DPH;
        #pragma unroll
        for (int dt = 0; dt < 4; ++dt)
            orow[dt * 16 + fr] = acc[dt][r] * inv;
    }
}

extern "C" void kernel_launch(void* const* d_in, const int* in_sizes, int n_in,
                              void* d_out, int out_size, void* d_ws, size_t ws_size,
                              hipStream_t stream)
{
    (void)in_sizes; (void)n_in; (void)out_size; (void)d_ws; (void)ws_size;
    const float* Q   = (const float*)d_in[0];
    const float* K   = (const float*)d_in[1];
    const float* V   = (const float*)d_in[2];
    const int*   msk = (const int*)d_in[3];
    const float* dm  = (const float*)d_in[4];
    float* o = (float*)d_out;

    dim3 grid(Bn * Hn * (Sn / QB));   // 2048 blocks
    dim3 block(256);                  // 4 waves
    mha_fwd<<<grid, block, 0, stream>>>(Q, K, V, msk, dm, o);
}